// Round 7
// baseline (84.985 us; speedup 1.0000x reference)
//
#include <hip/hip_runtime.h>
#include <hip/hip_fp16.h>
#include <math.h>

#define PATCH 41
#define PSIZE (PATCH * PATCH)   // 1681
#define NUM_ANG 8
#define KS 16
#define STRIDE 10
#define PAD 4
#define DESC 128
#define CLIPVAL 0.2f

#define OSTRIDE 44               // s_o/s_m row stride (quad stores 16B-aligned)
#define CSTRIDE 36               // colsum row stride (float4-aligned, 2-way banks)
#define ROWQ 11                  // 4-pixel quads per row (last is 1 pixel)
#define NQUAD (PATCH * ROWQ)     // 451

__device__ __forceinline__ float wave_sum64(float v) {
    #pragma unroll
    for (int off = 32; off >= 1; off >>= 1) v += __shfl_xor(v, off);
    return v;
}

// gradient -> (orientation in octant units [0,8], gaussian-weighted magnitude x1024)
__device__ __forceinline__ float2 grad_om(float gx, float gy, float gkv) {
    const float mag = sqrtf(gx * gx + gy * gy + 1e-10f) * gkv * 1024.0f;
    const float gxp = gx + 1e-10f;
    const float ax = fabsf(gxp), ay = fabsf(gy);
    const float mx = fmaxf(fmaxf(ax, ay), 1e-20f);
    const float t  = fminf(ax, ay) / mx;
    const float s  = t * t;
    float r = t * (1.27306897f + s * (-0.42055650f + s * (0.22936229f
                  + s * (-0.10839420f + s * 0.02652810f))));
    if (ay > ax)     r = 2.0f - r;
    if (gxp < 0.0f)  r = 4.0f - r;
    if (gy < 0.0f)   r = 8.0f - r;          // in [0, 8]
    return make_float2(r, mag);
}

__global__ __launch_bounds__(64) void sift_desc_kernel(
    const float* __restrict__ input,
    const float* __restrict__ gk,
    float* __restrict__ out)
{
    __shared__ float  s_o[PATCH * OSTRIDE];     // 7216 B
    __shared__ __half s_m[PATCH * OSTRIDE];     // 3608 B
    __shared__ float  s_cs[PATCH * CSTRIDE];    // 5904 B

    const int lane = threadIdx.x;               // 0..63, one wave per patch
    const int b    = blockIdx.x;
    const float* in_p = input + (size_t)b * PSIZE;

    // exact separable pooling weights: w1r[d] = (d<8 ? d+0.5 : 15.5-d)/8
    const float w1r[KS] = {0.0625f, 0.1875f, 0.3125f, 0.4375f,
                           0.5625f, 0.6875f, 0.8125f, 0.9375f,
                           0.9375f, 0.8125f, 0.6875f, 0.5625f,
                           0.4375f, 0.3125f, 0.1875f, 0.0625f};

    // ---- phase 1: gradients from global (VMEM pipe) -> (o f32, m f16) in LDS ----
    for (int q = lane; q < NQUAD; q += 64) {
        const int y  = q / ROWQ;
        const int xq = (q - y * ROWQ) * 4;
        const int ym = max(y - 1, 0), yp = min(y + 1, PATCH - 1);
        const float* cr = in_p + y  * PATCH;
        const float* ur = in_p + ym * PATCH;
        const float* dr = in_p + yp * PATCH;
        const float* gr = gk + y * PATCH;
        const int base = y * OSTRIDE + xq;

        if (xq < 40) {           // 4-pixel quad, x = xq..xq+3 (<= 39)
            float c0 = cr[xq], c1 = cr[xq+1], c2 = cr[xq+2], c3 = cr[xq+3];
            float L  = cr[max(xq - 1, 0)];
            float R  = cr[xq + 4];
            float u0 = ur[xq], u1 = ur[xq+1], u2 = ur[xq+2], u3 = ur[xq+3];
            float d0 = dr[xq], d1 = dr[xq+1], d2 = dr[xq+2], d3 = dr[xq+3];

            float2 om0 = grad_om(0.5f*(c1 - L),  0.5f*(d0 - u0), gr[xq]);
            float2 om1 = grad_om(0.5f*(c2 - c0), 0.5f*(d1 - u1), gr[xq+1]);
            float2 om2 = grad_om(0.5f*(c3 - c1), 0.5f*(d2 - u2), gr[xq+2]);
            float2 om3 = grad_om(0.5f*(R  - c2), 0.5f*(d3 - u3), gr[xq+3]);

            *(float4*)(s_o + base) = make_float4(om0.x, om1.x, om2.x, om3.x);
            *(__half2*)(s_m + base)     = __floats2half2_rn(om0.y, om1.y);
            *(__half2*)(s_m + base + 2) = __floats2half2_rn(om2.y, om3.y);
        } else {                 // ragged tail: single pixel x = 40
            float2 om = grad_om(0.5f*(cr[40] - cr[39]),
                                0.5f*(dr[40] - ur[40]), gr[40]);
            s_o[base] = om.x;
            s_m[base] = __float2half(om.y);
        }
    }
    __syncthreads();

    // ---- phase 2a: x-pooling; item (y, j) owns all 8 angle accumulators ----
    // hat_a(o) = relu(1 - |o - a|)  (+ relu(1 - |o - 8|) folded into a = 0)
    #pragma unroll
    for (int pass = 0; pass < 3; ++pass) {
        const int item = lane + pass * 64;
        if (item < PATCH * 4) {
            const int y = item >> 2;
            const int j = item & 3;
            const int px0 = j * STRIDE - PAD;
            const float*  po = s_o + y * OSTRIDE;
            const __half* pm = s_m + y * OSTRIDE;

            float acc[NUM_ANG];
            #pragma unroll
            for (int a = 0; a < NUM_ANG; ++a) acc[a] = 0.0f;

            #pragma unroll
            for (int dx = 0; dx < KS; ++dx) {
                const int px  = px0 + dx;
                const int pxc = min(max(px, 0), PATCH - 1);
                const float wv = (px == pxc) ? w1r[dx] : 0.0f;
                const float o  = po[pxc];
                const float mw = __half2float(pm[pxc]) * wv;
                #pragma unroll
                for (int a = 0; a < NUM_ANG; ++a) {
                    const float t = fmaxf(0.0f, 1.0f - fabsf(o - (float)a));
                    acc[a] = fmaf(t, mw, acc[a]);
                }
                const float t8 = fmaxf(0.0f, 1.0f - fabsf(o - 8.0f));
                acc[0] = fmaf(t8, mw, acc[0]);
            }
            const int cbase = y * CSTRIDE + j * 8;
            *(float4*)(s_cs + cbase)     = make_float4(acc[0], acc[1], acc[2], acc[3]);
            *(float4*)(s_cs + cbase + 4) = make_float4(acc[4], acc[5], acc[6], acc[7]);
        }
    }
    __syncthreads();

    // ---- phase 2b: y-pooling; each lane owns descriptor items lane, lane+64 ----
    float v0 = 0.0f, v1 = 0.0f;
    #pragma unroll
    for (int h = 0; h < 2; ++h) {
        const int item = lane + h * 64;
        const int a  = item & 7;
        const int jj = (item >> 3) & 3;
        const int ii = item >> 5;
        const int py0 = ii * STRIDE - PAD;
        float s = 0.0f;
        #pragma unroll
        for (int dy = 0; dy < KS; ++dy) {
            const int py  = py0 + dy;
            const int pyc = min(max(py, 0), PATCH - 1);
            const float wv = (py == pyc) ? w1r[dy] : 0.0f;
            s = fmaf(wv, s_cs[pyc * CSTRIDE + jj * 8 + a], s);
        }
        if (h == 0) v0 = s; else v1 = s;
    }

    // ---- normalization chain (pure wave shuffles): l2n -> clip -> l2n -> rootsift ----
    const float ss1 = wave_sum64(v0 * v0 + v1 * v1);
    const float inv1 = 1.0f / fmaxf(sqrtf(ss1), 1e-12f);
    float a0 = fminf(fmaxf(v0 * inv1, 0.0f), CLIPVAL);
    float a1 = fminf(fmaxf(v1 * inv1, 0.0f), CLIPVAL);

    const float ss2 = wave_sum64(a0 * a0 + a1 * a1);
    const float inv2 = 1.0f / fmaxf(sqrtf(ss2), 1e-12f);
    const float b0 = a0 * inv2;
    const float b1 = a1 * inv2;

    const float l1 = wave_sum64(fabsf(b0) + fabsf(b1));
    const float invl = 1.0f / fmaxf(l1, 1e-12f);
    const float o0 = sqrtf(b0 * invl + 1e-10f);
    const float o1 = sqrtf(b1 * invl + 1e-10f);

    // reference layout: desc[ang*16 + i*4 + j]
    {
        const int a  = lane & 7, jj = (lane >> 3) & 3, ii = lane >> 5;
        out[(size_t)b * DESC + (a * 16 + ii * 4 + jj)] = o0;
        const int item = lane + 64;
        const int a2 = item & 7, jj2 = (item >> 3) & 3, ii2 = item >> 5;
        out[(size_t)b * DESC + (a2 * 16 + ii2 * 4 + jj2)] = o1;
    }
}

extern "C" void kernel_launch(void* const* d_in, const int* in_sizes, int n_in,
                              void* d_out, int out_size, void* d_ws, size_t ws_size,
                              hipStream_t stream) {
    const float* input = (const float*)d_in[0];
    const float* gk    = (const float*)d_in[1];
    float* out         = (float*)d_out;

    const int B = in_sizes[0] / PSIZE;
    if (B <= 0) return;
    sift_desc_kernel<<<dim3(B), dim3(64), 0, stream>>>(input, gk, out);
}